// Round 1
// baseline (289.050 us; speedup 1.0000x reference)
//
#include <hip/hip_runtime.h>
#include <math.h>

#define D 128
#define BI 128
#define BJ 128
#define NSPLIT 4
#define SHIFT 10.0f
#define INVT 10.0f
#define NBINS 512

// ---------------- normalize rows + expand labels + label histogram ----------
__global__ __launch_bounds__(256)
void norm_hist_kernel(const float* __restrict__ f, const int* __restrict__ labels,
                      float* __restrict__ fn, int* __restrict__ labm,
                      int* __restrict__ hist, int M, int nrep)
{
    int gw = (blockIdx.x * blockDim.x + threadIdx.x) >> 6;  // one wave per row
    int lane = threadIdx.x & 63;
    if (gw >= M) return;
    const float2 v = *reinterpret_cast<const float2*>(&f[(size_t)gw * D + lane * 2]);
    float ss = v.x * v.x + v.y * v.y;
    #pragma unroll
    for (int m = 1; m < 64; m <<= 1) ss += __shfl_xor(ss, m);
    float inv = 1.0f / fmaxf(sqrtf(ss), 1e-12f);
    float2 o; o.x = v.x * inv; o.y = v.y * inv;
    *reinterpret_cast<float2*>(&fn[(size_t)gw * D + lane * 2]) = o;
    if (lane == 0) {
        int lb = labels[gw / nrep];
        labm[gw] = lb;
        atomicAdd(&hist[lb], 1);
    }
}

// ---------------- main: tiled fp32 "GEMM" + fused exp/mask accumulation -----
// 256 threads = 16x16 grid; each thread owns an 8x8 block of the 128x128 tile.
// LDS tiles stored as float4 with XOR swizzle: slot = row*32 + (c4 ^ (row&7)).
// Since per-thread rows are ty+16r (row&7 == ty&7 const) and cols tx+16c,
// the XOR key is a per-thread constant -> cheap addressing, conflict-free-ish.
__global__ __launch_bounds__(256)
void supcon_main(const float* __restrict__ fn, const int* __restrict__ labm,
                 float* __restrict__ Epart, float* __restrict__ Ppart,
                 int M, int jchunk)
{
    __shared__ float4 FiS[BI * 32];
    __shared__ float4 FjS[BJ * 32];

    const int tid = threadIdx.x;
    const int tx = tid & 15;
    const int ty = tid >> 4;
    const int i0 = blockIdx.x * BI;
    const int j0 = blockIdx.y * jchunk;
    const int kA = ty & 7;
    const int kB = tx & 7;

    // stage Fi once (swizzled)
    #pragma unroll
    for (int k = 0; k < 16; ++k) {
        int idx = k * 256 + tid;
        int r = idx >> 5, c4 = idx & 31;
        float4 v = *reinterpret_cast<const float4*>(&fn[(size_t)(i0 + r) * D + c4 * 4]);
        FiS[r * 32 + (c4 ^ (r & 7))] = v;
    }

    int li[8];
    #pragma unroll
    for (int r = 0; r < 8; ++r) li[r] = labm[i0 + ty + 16 * r];

    float Eloc[8], Ploc[8];
    #pragma unroll
    for (int r = 0; r < 8; ++r) { Eloc[r] = 0.f; Ploc[r] = 0.f; }

    for (int jt = 0; jt < jchunk; jt += BJ) {
        const int jb = j0 + jt;
        __syncthreads();  // protect FjS from previous iteration's readers
        #pragma unroll
        for (int k = 0; k < 16; ++k) {
            int idx = k * 256 + tid;
            int r = idx >> 5, c4 = idx & 31;
            float4 v = *reinterpret_cast<const float4*>(&fn[(size_t)(jb + r) * D + c4 * 4]);
            FjS[r * 32 + (c4 ^ (r & 7))] = v;
        }
        __syncthreads();

        float acc[8][8];
        #pragma unroll
        for (int r = 0; r < 8; ++r)
            #pragma unroll
            for (int c = 0; c < 8; ++c) acc[r][c] = 0.f;

        // K = 128 entirely inside this tile: complete dot products per pass
        #pragma unroll 4
        for (int d4 = 0; d4 < 32; ++d4) {
            float4 a[8], b[8];
            #pragma unroll
            for (int r = 0; r < 8; ++r) a[r] = FiS[(ty + 16 * r) * 32 + (d4 ^ kA)];
            #pragma unroll
            for (int c = 0; c < 8; ++c) b[c] = FjS[(tx + 16 * c) * 32 + (d4 ^ kB)];
            #pragma unroll
            for (int r = 0; r < 8; ++r)
                #pragma unroll
                for (int c = 0; c < 8; ++c) {
                    acc[r][c] = fmaf(a[r].x, b[c].x, acc[r][c]);
                    acc[r][c] = fmaf(a[r].y, b[c].y, acc[r][c]);
                    acc[r][c] = fmaf(a[r].z, b[c].z, acc[r][c]);
                    acc[r][c] = fmaf(a[r].w, b[c].w, acc[r][c]);
                }
        }

        // fused epilogue: exp-sum (diag excluded) + masked positive-sum
        int lj[8];
        #pragma unroll
        for (int c = 0; c < 8; ++c) lj[c] = labm[jb + tx + 16 * c];
        #pragma unroll
        for (int r = 0; r < 8; ++r) {
            const int gi = i0 + ty + 16 * r;
            float esum = 0.f, psum = 0.f;
            #pragma unroll
            for (int c = 0; c < 8; ++c) {
                const int gj = jb + tx + 16 * c;
                float s = acc[r][c] * INVT;
                float e = __expf(s - SHIFT);          // s <= 10 always
                bool nd = (gi != gj);
                esum += (nd ? e : 0.f);
                psum += ((nd && (li[r] == lj[c])) ? s : 0.f);
            }
            Eloc[r] += esum;
            Ploc[r] += psum;
        }
    }

    // reduce over the 16 column-threads (lane bits 0..3) and store partials
    #pragma unroll
    for (int r = 0; r < 8; ++r) {
        float e = Eloc[r], p = Ploc[r];
        #pragma unroll
        for (int m = 1; m <= 8; m <<= 1) {
            e += __shfl_xor(e, m);
            p += __shfl_xor(p, m);
        }
        if (tx == 0) {
            int gi = i0 + ty + 16 * r;
            Epart[(size_t)blockIdx.y * M + gi] = e;
            Ppart[(size_t)blockIdx.y * M + gi] = p;
        }
    }
}

// ---------------- final reduction to scalar loss ----------------------------
__global__ __launch_bounds__(256)
void reduce_loss(const float* __restrict__ Epart, const float* __restrict__ Ppart,
                 const int* __restrict__ labm, const int* __restrict__ hist,
                 float* __restrict__ out, int M)
{
    int i = blockIdx.x * blockDim.x + threadIdx.x;
    float term = 0.f;
    if (i < M) {
        float E = 0.f, P = 0.f;
        #pragma unroll
        for (int k = 0; k < NSPLIT; ++k) {
            E += Epart[(size_t)k * M + i];
            P += Ppart[(size_t)k * M + i];
        }
        float cnt = (float)(hist[labm[i]] - 1);   // >= 1: same-sample partner exists
        term = (SHIFT + logf(E)) - P / cnt;
    }
    #pragma unroll
    for (int m = 1; m < 64; m <<= 1) term += __shfl_xor(term, m);
    if ((threadIdx.x & 63) == 0) atomicAdd(out, term / (float)M);
}

extern "C" void kernel_launch(void* const* d_in, const int* in_sizes, int n_in,
                              void* d_out, int out_size, void* d_ws, size_t ws_size,
                              hipStream_t stream)
{
    const float* feats = (const float*)d_in[0];
    const int* labels = (const int*)d_in[1];
    const int Bn = in_sizes[1];
    const int M = in_sizes[0] / D;     // 8192
    const int nrep = M / Bn;           // 2

    char* ws = (char*)d_ws;
    float* fn = (float*)ws;
    size_t off = (size_t)M * D * sizeof(float);
    int* labm = (int*)(ws + off); off += (size_t)M * sizeof(int);
    int* hist = (int*)(ws + off); off += (size_t)NBINS * sizeof(int);
    off = (off + 255) & ~(size_t)255;
    float* Ep = (float*)(ws + off); off += (size_t)NSPLIT * M * sizeof(float);
    float* Pp = (float*)(ws + off); off += (size_t)NSPLIT * M * sizeof(float);

    hipMemsetAsync(hist, 0, NBINS * sizeof(int), stream);
    hipMemsetAsync(d_out, 0, sizeof(float), stream);

    norm_hist_kernel<<<(M + 3) / 4, 256, 0, stream>>>(feats, labels, fn, labm, hist, M, nrep);

    const int jchunk = M / NSPLIT;
    dim3 grid(M / BI, NSPLIT);
    supcon_main<<<grid, 256, 0, stream>>>(fn, labm, Ep, Pp, M, jchunk);

    reduce_loss<<<(M + 255) / 256, 256, 0, stream>>>(Ep, Pp, labm, hist, (float*)d_out, M);
}

// Round 2
// 99.447 us; speedup vs baseline: 2.9066x; 2.9066x over previous
//
#include <hip/hip_runtime.h>
#include <math.h>

#define DD 128
#define NSPLIT 16
#define NBINS 512
#define SHIFT 10.0f
#define L2E_T 14.4269504089f   // 10 * log2(e)

typedef _Float16 f16x8 __attribute__((ext_vector_type(8)));
typedef _Float16 f16x2 __attribute__((ext_vector_type(2)));
typedef float f32x4 __attribute__((ext_vector_type(4)));

// ---- normalize rows (fp32), emit f16 copy, labels, histogram, label-sums G ----
__global__ __launch_bounds__(256)
void norm_kernel(const float* __restrict__ f, const int* __restrict__ labels,
                 float* __restrict__ fn, _Float16* __restrict__ fh,
                 int* __restrict__ labm, int* __restrict__ hist,
                 float* __restrict__ G, int M, int nrep)
{
    int gw = (blockIdx.x * 256 + threadIdx.x) >> 6;   // one wave per row
    int lane = threadIdx.x & 63;
    if (gw >= M) return;
    float2 v = *reinterpret_cast<const float2*>(&f[(size_t)gw * DD + lane * 2]);
    float ss = v.x * v.x + v.y * v.y;
    #pragma unroll
    for (int m = 1; m < 64; m <<= 1) ss += __shfl_xor(ss, m);
    float inv = 1.0f / fmaxf(sqrtf(ss), 1e-12f);
    float2 o; o.x = v.x * inv; o.y = v.y * inv;
    *reinterpret_cast<float2*>(&fn[(size_t)gw * DD + lane * 2]) = o;
    f16x2 h; h[0] = (_Float16)o.x; h[1] = (_Float16)o.y;
    *reinterpret_cast<f16x2*>(&fh[(size_t)gw * DD + lane * 2]) = h;
    int lb = labels[gw / nrep];
    atomicAdd(&G[lb * DD + lane * 2],     o.x);
    atomicAdd(&G[lb * DD + lane * 2 + 1], o.y);
    if (lane == 0) { labm[gw] = lb; atomicAdd(&hist[lb], 1); }
}

// ---- main: f16 MFMA over all pairs, fused exp-sum. No LDS, no masks. ----
// Block: 256 thr = 4 waves. Wave w owns 32 i-rows (2 subtiles of 16), whose
// B-fragments stay in registers for the whole kernel. j streams in 16-row
// tiles; all 4 waves read the same A-fragments (L1 reuse). Computes S^T
// tiles D[j][i] = dot(Fj, Fi) via mfma(A=Fj, B=Fi): i is lane-local
// (col = lane&15), so E_i accumulates per-lane; j varies over (lane>>4, reg).
__global__ __launch_bounds__(256, 4)
void supcon_main(const _Float16* __restrict__ fh, float* __restrict__ Epart,
                 int M, int jchunk)
{
    const int lane = threadIdx.x & 63;
    const int w = threadIdx.x >> 6;
    const int ibase = blockIdx.x * 128 + w * 32;
    const int rowsel = lane & 15;
    const int ksel = (lane >> 4) * 8;     // f16 k-offset within 32-wide K step

    // register-resident Fi fragments: 2 subtiles x 4 K-steps
    f16x8 bfr[2][4];
    #pragma unroll
    for (int t = 0; t < 2; ++t)
        #pragma unroll
        for (int kk = 0; kk < 4; ++kk)
            bfr[t][kk] = *reinterpret_cast<const f16x8*>(
                &fh[(size_t)(ibase + t * 16 + rowsel) * DD + kk * 32 + ksel]);

    float esum[2] = {0.f, 0.f};
    const int jstart = blockIdx.y * jchunk;
    const int ntile = jchunk >> 4;        // 16 j per tile

    for (int jt = 0; jt < ntile; ++jt) {
        const int j0 = jstart + jt * 16;
        f16x8 afr[4];
        #pragma unroll
        for (int kk = 0; kk < 4; ++kk)
            afr[kk] = *reinterpret_cast<const f16x8*>(
                &fh[(size_t)(j0 + rowsel) * DD + kk * 32 + ksel]);
        #pragma unroll
        for (int t = 0; t < 2; ++t) {
            f32x4 acc = {0.f, 0.f, 0.f, 0.f};
            #pragma unroll
            for (int kk = 0; kk < 4; ++kk)
                acc = __builtin_amdgcn_mfma_f32_16x16x32_f16(afr[kk], bfr[t][kk], acc, 0, 0, 0);
            #pragma unroll
            for (int r = 0; r < 4; ++r)
                esum[t] += exp2f(__builtin_fmaf(acc[r], L2E_T, -L2E_T)); // exp(s-10)
        }
    }

    // lane groups (bits 4,5) hold different j-rows of the same i: fold them
    #pragma unroll
    for (int t = 0; t < 2; ++t) {
        float e = esum[t];
        e += __shfl_xor(e, 16);
        e += __shfl_xor(e, 32);
        if (lane < 16)
            Epart[(size_t)blockIdx.y * M + ibase + t * 16 + lane] = e;
    }
}

// ---- per-row loss term: E from partials, P from label-sum dot ----
__global__ __launch_bounds__(256)
void final1(const float* __restrict__ fn, const float* __restrict__ Epart,
            const int* __restrict__ labm, const int* __restrict__ hist,
            const float* __restrict__ G, float* __restrict__ term, int M)
{
    int i = (blockIdx.x * 256 + threadIdx.x) >> 6;   // wave per row
    int lane = threadIdx.x & 63;
    if (i >= M) return;
    int lb = labm[i];
    float2 v = *reinterpret_cast<const float2*>(&fn[(size_t)i * DD + lane * 2]);
    float2 g = *reinterpret_cast<const float2*>(&G[lb * DD + lane * 2]);
    float gd = v.x * g.x + v.y * g.y;   // f_i . G[lab_i]
    float sd = v.x * v.x + v.y * v.y;   // f_i . f_i
    #pragma unroll
    for (int m = 1; m < 64; m <<= 1) { gd += __shfl_xor(gd, m); sd += __shfl_xor(sd, m); }
    float e = (lane < NSPLIT) ? Epart[(size_t)lane * M + i] : 0.f;
    #pragma unroll
    for (int m = 1; m < 16; m <<= 1) e += __shfl_xor(e, m);
    if (lane == 0) {
        float E = e - 1.0f;                        // drop diagonal exp(0)
        float cnt = (float)(hist[lb] - 1);
        float P_over_cnt = SHIFT * (gd - sd) / cnt;
        term[i] = (SHIFT + logf(E)) - P_over_cnt;  // lse_i - P_i/cnt_i
    }
}

__global__ __launch_bounds__(256)
void final2(const float* __restrict__ term, float* __restrict__ out, int M)
{
    __shared__ float red[4];
    float s = 0.f;
    for (int i = threadIdx.x; i < M; i += 256) s += term[i];
    #pragma unroll
    for (int m = 1; m < 64; m <<= 1) s += __shfl_xor(s, m);
    int lane = threadIdx.x & 63, wv = threadIdx.x >> 6;
    if (lane == 0) red[wv] = s;
    __syncthreads();
    if (threadIdx.x == 0)
        out[0] = (red[0] + red[1] + red[2] + red[3]) / (float)M;
}

extern "C" void kernel_launch(void* const* d_in, const int* in_sizes, int n_in,
                              void* d_out, int out_size, void* d_ws, size_t ws_size,
                              hipStream_t stream)
{
    const float* feats = (const float*)d_in[0];
    const int* labels = (const int*)d_in[1];
    const int Bn = in_sizes[1];
    const int M = in_sizes[0] / DD;    // 8192
    const int nrep = M / Bn;           // 2

    char* ws = (char*)d_ws;
    float* fn = (float*)ws;
    size_t off = (size_t)M * DD * sizeof(float);
    _Float16* fh = (_Float16*)(ws + off); off += (size_t)M * DD * sizeof(_Float16);
    int* labm = (int*)(ws + off); off += (size_t)M * sizeof(int);
    int* hist = (int*)(ws + off); off += (size_t)NBINS * sizeof(int);
    off = (off + 255) & ~(size_t)255;
    float* G = (float*)(ws + off); off += (size_t)NBINS * DD * sizeof(float);
    float* Epart = (float*)(ws + off); off += (size_t)NSPLIT * M * sizeof(float);
    float* term = (float*)(ws + off); off += (size_t)M * sizeof(float);

    hipMemsetAsync(G, 0, (size_t)NBINS * DD * sizeof(float), stream);
    hipMemsetAsync(hist, 0, NBINS * sizeof(int), stream);

    norm_kernel<<<M / 4, 256, 0, stream>>>(feats, labels, fn, fh, labm, hist, G, M, nrep);

    const int jchunk = M / NSPLIT;     // 512
    dim3 grid(M / 128, NSPLIT);        // 64 x 16 = 1024 blocks
    supcon_main<<<grid, 256, 0, stream>>>(fh, Epart, M, jchunk);

    final1<<<M / 4, 256, 0, stream>>>(fn, Epart, labm, hist, G, term, M);
    final2<<<1, 256, 0, stream>>>(term, (float*)d_out, M);
}